// Round 3
// baseline (733.223 us; speedup 1.0000x reference)
//
#include <hip/hip_runtime.h>
#include <stdint.h>

typedef __bf16 bf16x8 __attribute__((ext_vector_type(8)));
typedef float f32x4 __attribute__((ext_vector_type(4)));
typedef unsigned short ushort8v __attribute__((ext_vector_type(8)));

__device__ __forceinline__ unsigned short f2bf(float f) {
  union { float f; unsigned int u; } x; x.f = f;
  unsigned int r = x.u + 0x7FFFu + ((x.u >> 16) & 1u);
  return (unsigned short)(r >> 16);
}

__device__ __forceinline__ float ftanh(float x) {
  float ax = fabsf(x);
  float e = __expf(-2.0f * ax);
  float r = (1.0f - e) / (1.0f + e);
  return copysignf(r, x);
}

// ---------------- W1 f32 -> bf16 convert ----------------
__global__ __launch_bounds__(256) void w1cvt_kernel(
    const float* __restrict__ W1, unsigned short* __restrict__ w1b) {
  const int idx = (blockIdx.x * 256 + threadIdx.x) * 8;
  const float4 v0 = *(const float4*)(W1 + idx);
  const float4 v1 = *(const float4*)(W1 + idx + 4);
  ushort8v o;
  o[0] = f2bf(v0.x); o[1] = f2bf(v0.y); o[2] = f2bf(v0.z); o[3] = f2bf(v0.w);
  o[4] = f2bf(v1.x); o[5] = f2bf(v1.y); o[6] = f2bf(v1.z); o[7] = f2bf(v1.w);
  *(ushort8v*)(w1b + idx) = o;
}

// ---------------- u[b][a] = sum_d dec[b][d] * W2[a][d] ----------------
__global__ __launch_bounds__(256) void dec_proj_kernel(
    const float* __restrict__ dec, const float* __restrict__ W2,
    float* __restrict__ u) {
  __shared__ __align__(16) float w2s[1024];
  const int a = blockIdx.x;
  const int t = threadIdx.x;
  *(float4*)(w2s + t * 4) = *(const float4*)(W2 + (size_t)a * 1024 + t * 4);
  __syncthreads();
  const int wid = t >> 6, l = t & 63;
  for (int bi = 0; bi < 8; ++bi) {
    const int b = wid * 8 + bi;
    const float* dp = dec + (size_t)b * 1024;
    float acc = 0.f;
#pragma unroll
    for (int i = 0; i < 4; ++i) {
      const int k = i * 256 + l * 4;
      const float4 dv = *(const float4*)(dp + k);
      const float4 wv = *(const float4*)(w2s + k);
      acc = fmaf(dv.x, wv.x, acc); acc = fmaf(dv.y, wv.y, acc);
      acc = fmaf(dv.z, wv.z, acc); acc = fmaf(dv.w, wv.w, acc);
    }
#pragma unroll
    for (int m = 1; m < 64; m <<= 1) acc += __shfl_xor(acc, m, 64);
    if (l == 0) u[(size_t)b * 1024 + a] = acc;
  }
}

// ---------------- fused scores: v . tanh(enc@W1^T + u) ----------------
// grid 1024 (64 rows each), 512 threads (8 waves = 2 wr x 4 wc).
// enc K-quarter (64x256) staged in 32 KiB LDS (XOR-swizzled);
// W1 B-fragments read DIRECTLY from global (L2-resident 2 MB) -- no LDS-B.
__global__ __launch_bounds__(512, 2) void scores_kernel(
    const float* __restrict__ enc, const unsigned short* __restrict__ w1b,
    const float* __restrict__ u, const float* __restrict__ vvec,
    float* __restrict__ out) {
  __shared__ __align__(16) char encL[32768];
  __shared__ __align__(16) float sred[256];

  const int t = threadIdx.x;
  const int bid = blockIdx.x;
  const int m0 = bid * 64;
  const int b = bid >> 5; /* 32 blocks per batch (2048/64 rows) */
  const int l = t & 63, wid = t >> 6;
  const int wr = wid >> 2, wc = wid & 3;
  const int lm = l & 15, lg = l >> 4;

  f32x4 acc[8][4];
#pragma unroll
  for (int c1 = 0; c1 < 8; ++c1)
#pragma unroll
    for (int c2 = 0; c2 < 4; ++c2) acc[c1][c2] = (f32x4){0.f, 0.f, 0.f, 0.f};

  const int row_a0 = wr * 32 + lm; /* a1 row is +16: same (row&7) swizzle */
  const int aswz = (row_a0 & 7) << 4;
  const int abase0 = row_a0 * 512;
  // per-lane B byte base: a_local = wc*32 + lm, k-slot lg
  const char* w1c = (const char*)w1b;
  const char* bbase = w1c + (wc * 32 + lm) * 2048 + lg * 16;

  for (int kq = 0; kq < 4; ++kq) {
    if (kq) __syncthreads(); /* all waves done reading prev enc quarter */
    // stage enc quarter: 64 rows x 256 k, f32 -> bf16, XOR-swizzled
#pragma unroll
    for (int it = 0; it < 4; ++it) {
      const int c = it * 512 + t;
      const int row = c >> 5;
      const int k0 = (c & 31) * 8;
      const float* g = enc + (size_t)(m0 + row) * 1024 + kq * 256 + k0;
      const float4 v0 = *(const float4*)g;
      const float4 v1 = *(const float4*)(g + 4);
      ushort8v o;
      o[0] = f2bf(v0.x); o[1] = f2bf(v0.y); o[2] = f2bf(v0.z); o[3] = f2bf(v0.w);
      o[4] = f2bf(v1.x); o[5] = f2bf(v1.y); o[6] = f2bf(v1.z); o[7] = f2bf(v1.w);
      const int dest = row * 512 + ((k0 * 2) ^ ((row & 7) << 4));
      *(ushort8v*)(encL + dest) = o;
    }
    __syncthreads(); /* enc quarter visible */

    const char* wk = bbase + kq * 512; /* + kq*256 k-elements */
#pragma unroll
    for (int ch = 0; ch < 8; ++ch) {
      const char* wch = wk + ch * 262144; /* + ch*128 a-rows */
#pragma unroll
      for (int kk = 0; kk < 8; ++kk) {
        const bf16x8 b0 = *(const bf16x8*)(wch + kk * 64);
        const bf16x8 b1 = *(const bf16x8*)(wch + kk * 64 + 32768);
        const int koff = (kk * 64 + lg * 16) ^ aswz;
        const bf16x8 a0 = *(const bf16x8*)(encL + abase0 + koff);
        const bf16x8 a1 = *(const bf16x8*)(encL + abase0 + 8192 + koff);
        acc[ch][0] = __builtin_amdgcn_mfma_f32_16x16x32_bf16(a0, b0, acc[ch][0], 0, 0, 0);
        acc[ch][1] = __builtin_amdgcn_mfma_f32_16x16x32_bf16(a1, b0, acc[ch][1], 0, 0, 0);
        acc[ch][2] = __builtin_amdgcn_mfma_f32_16x16x32_bf16(a0, b1, acc[ch][2], 0, 0, 0);
        acc[ch][3] = __builtin_amdgcn_mfma_f32_16x16x32_bf16(a1, b1, acc[ch][3], 0, 0, 0);
      }
    }
  }

  // epilogue: tanh + v-weighted column reduction over all chunks
  f32x4 rowp0 = {0.f, 0.f, 0.f, 0.f}, rowp1 = {0.f, 0.f, 0.f, 0.f};
  const float* ub = u + (size_t)b * 1024;
#pragma unroll
  for (int ch = 0; ch < 8; ++ch) {
    const int colA = ch * 128 + wc * 32 + lm;
    const float uu0 = ub[colA], vv0 = vvec[colA];
    const float uu1 = ub[colA + 16], vv1 = vvec[colA + 16];
#pragma unroll
    for (int j = 0; j < 4; ++j) {
      rowp0[j] += ftanh(acc[ch][0][j] + uu0) * vv0;
      rowp1[j] += ftanh(acc[ch][1][j] + uu0) * vv0;
      rowp0[j] += ftanh(acc[ch][2][j] + uu1) * vv1;
      rowp1[j] += ftanh(acc[ch][3][j] + uu1) * vv1;
    }
  }
  // reduce over the 16 col-lanes (lm) of each fragment group
#pragma unroll
  for (int m = 1; m < 16; m <<= 1) {
#pragma unroll
    for (int j = 0; j < 4; ++j) {
      rowp0[j] += __shfl_xor(rowp0[j], m, 64);
      rowp1[j] += __shfl_xor(rowp1[j], m, 64);
    }
  }
  if (lm == 0) {
#pragma unroll
    for (int j = 0; j < 4; ++j) {
      sred[wc * 64 + wr * 32 + lg * 4 + j] = rowp0[j];
      sred[wc * 64 + wr * 32 + 16 + lg * 4 + j] = rowp1[j];
    }
  }
  __syncthreads();
  if (t < 64) {
    out[32768 + m0 + t] =
        sred[t] + sred[64 + t] + sred[128 + t] + sred[192 + t];
  }
}

// ---------------- masked softmax over L, in place on out[32768..] --------
__global__ __launch_bounds__(256) void softmax_kernel(
    float* __restrict__ out, const int* __restrict__ mask) {
  __shared__ float wred[4];
  const int bidx = blockIdx.x;
  const int t = threadIdx.x;
  float* sc = out + 32768 + (size_t)bidx * 2048;
  const int* mk = mask + (size_t)bidx * 2048;
  const float4 s0 = *(const float4*)(sc + t * 8);
  const float4 s1 = *(const float4*)(sc + t * 8 + 4);
  const int4 q0 = *(const int4*)(mk + t * 8);
  const int4 q1 = *(const int4*)(mk + t * 8 + 4);
  float v[8] = {s0.x, s0.y, s0.z, s0.w, s1.x, s1.y, s1.z, s1.w};
  int q[8] = {q0.x, q0.y, q0.z, q0.w, q1.x, q1.y, q1.z, q1.w};
  float mx = -3.0e38f;
#pragma unroll
  for (int j = 0; j < 8; ++j) if (q[j] != 0) mx = fmaxf(mx, v[j]);
#pragma unroll
  for (int m = 1; m < 64; m <<= 1) mx = fmaxf(mx, __shfl_xor(mx, m, 64));
  if ((t & 63) == 0) wred[t >> 6] = mx;
  __syncthreads();
  mx = fmaxf(fmaxf(wred[0], wred[1]), fmaxf(wred[2], wred[3]));
  __syncthreads();
  float p[8]; float sum = 0.f;
#pragma unroll
  for (int j = 0; j < 8; ++j) {
    p[j] = (q[j] != 0) ? __expf(v[j] - mx) : 0.f;
    sum += p[j];
  }
#pragma unroll
  for (int m = 1; m < 64; m <<= 1) sum += __shfl_xor(sum, m, 64);
  if ((t & 63) == 0) wred[t >> 6] = sum;
  __syncthreads();
  sum = (wred[0] + wred[1]) + (wred[2] + wred[3]);
  const float inv = 1.0f / sum;
  const float4 o0 = {p[0] * inv, p[1] * inv, p[2] * inv, p[3] * inv};
  const float4 o1 = {p[4] * inv, p[5] * inv, p[6] * inv, p[7] * inv};
  *(float4*)(sc + t * 8) = o0;
  *(float4*)(sc + t * 8 + 4) = o1;
}

// ---------------- context[b][e] = sum_l attn[b][l] * enc[b][l][e] --------
__global__ __launch_bounds__(256) void context_kernel(
    const float* __restrict__ enc, float* __restrict__ out) {
  __shared__ __align__(16) float attnS[2048];
  __shared__ __align__(16) float red[8 * 128];
  const int bid = blockIdx.x;
  const int b = bid >> 3, ec = bid & 7;
  const int e0 = ec * 128;
  const int t = threadIdx.x;
  const float* attn = out + 32768 + (size_t)b * 2048;
#pragma unroll
  for (int i = 0; i < 8; ++i) attnS[i * 256 + t] = attn[i * 256 + t];
  __syncthreads();
  const int el = (t & 31) * 4;
  const int ls = t >> 5;
  f32x4 acc = {0.f, 0.f, 0.f, 0.f};
  const float* ebase = enc + (size_t)b * 2048 * 1024 + e0 + el;
  for (int l2 = ls; l2 < 2048; l2 += 8) {
    const float a = attnS[l2];
    const float4 ev = *(const float4*)(ebase + (size_t)l2 * 1024);
    acc[0] = fmaf(a, ev.x, acc[0]);
    acc[1] = fmaf(a, ev.y, acc[1]);
    acc[2] = fmaf(a, ev.z, acc[2]);
    acc[3] = fmaf(a, ev.w, acc[3]);
  }
  *(f32x4*)(red + ls * 128 + el) = acc;
  __syncthreads();
  if (t < 128) {
    float s = 0.f;
#pragma unroll
    for (int i = 0; i < 8; ++i) s += red[i * 128 + t];
    out[(size_t)b * 1024 + e0 + t] = s;
  }
}

extern "C" void kernel_launch(void* const* d_in, const int* in_sizes, int n_in,
                              void* d_out, int out_size, void* d_ws,
                              size_t ws_size, hipStream_t stream) {
  const float* enc = (const float*)d_in[0];
  const float* dec = (const float*)d_in[1];
  const int* mask = (const int*)d_in[2];
  const float* W1 = (const float*)d_in[3];
  const float* W2 = (const float*)d_in[4];
  const float* v = (const float*)d_in[5];
  float* out = (float*)d_out;
  char* ws = (char*)d_ws;
  unsigned short* w1b = (unsigned short*)ws; /* 2 MB bf16 W1 */
  float* u = (float*)(ws + (2u << 20));      /* 128 KB dec projection */

  w1cvt_kernel<<<512, 256, 0, stream>>>(W1, w1b);
  dec_proj_kernel<<<1024, 256, 0, stream>>>(dec, W2, u);
  scores_kernel<<<1024, 512, 0, stream>>>(enc, w1b, u, v, out);
  softmax_kernel<<<32, 256, 0, stream>>>(out, mask);
  context_kernel<<<256, 256, 0, stream>>>(enc, out);
}

// Round 4
// 715.196 us; speedup vs baseline: 1.0252x; 1.0252x over previous
//
#include <hip/hip_runtime.h>
#include <stdint.h>

typedef __bf16 bf16x8 __attribute__((ext_vector_type(8)));
typedef float f32x4 __attribute__((ext_vector_type(4)));
typedef unsigned short ushort8v __attribute__((ext_vector_type(8)));

__device__ __forceinline__ unsigned short f2bf(float f) {
  union { float f; unsigned int u; } x; x.f = f;
  unsigned int r = x.u + 0x7FFFu + ((x.u >> 16) & 1u);
  return (unsigned short)(r >> 16);
}

__device__ __forceinline__ float ftanh(float x) {
  float ax = fabsf(x);
  float e = __expf(-2.0f * ax);
  float r = (1.0f - e) / (1.0f + e);
  return copysignf(r, x);
}

// ---------------- W1 f32 -> bf16 convert ----------------
__global__ __launch_bounds__(256) void w1cvt_kernel(
    const float* __restrict__ W1, unsigned short* __restrict__ w1b) {
  const int idx = (blockIdx.x * 256 + threadIdx.x) * 8;
  const float4 v0 = *(const float4*)(W1 + idx);
  const float4 v1 = *(const float4*)(W1 + idx + 4);
  ushort8v o;
  o[0] = f2bf(v0.x); o[1] = f2bf(v0.y); o[2] = f2bf(v0.z); o[3] = f2bf(v0.w);
  o[4] = f2bf(v1.x); o[5] = f2bf(v1.y); o[6] = f2bf(v1.z); o[7] = f2bf(v1.w);
  *(ushort8v*)(w1b + idx) = o;
}

// ---------------- u[b][a] = sum_d dec[b][d] * W2[a][d] ----------------
__global__ __launch_bounds__(256) void dec_proj_kernel(
    const float* __restrict__ dec, const float* __restrict__ W2,
    float* __restrict__ u) {
  __shared__ __align__(16) float w2s[1024];
  const int a = blockIdx.x;
  const int t = threadIdx.x;
  *(float4*)(w2s + t * 4) = *(const float4*)(W2 + (size_t)a * 1024 + t * 4);
  __syncthreads();
  const int wid = t >> 6, l = t & 63;
  for (int bi = 0; bi < 8; ++bi) {
    const int b = wid * 8 + bi;
    const float* dp = dec + (size_t)b * 1024;
    float acc = 0.f;
#pragma unroll
    for (int i = 0; i < 4; ++i) {
      const int k = i * 256 + l * 4;
      const float4 dv = *(const float4*)(dp + k);
      const float4 wv = *(const float4*)(w2s + k);
      acc = fmaf(dv.x, wv.x, acc); acc = fmaf(dv.y, wv.y, acc);
      acc = fmaf(dv.z, wv.z, acc); acc = fmaf(dv.w, wv.w, acc);
    }
#pragma unroll
    for (int m = 1; m < 64; m <<= 1) acc += __shfl_xor(acc, m, 64);
    if (l == 0) u[(size_t)b * 1024 + a] = acc;
  }
}

// ---------------- fused scores: v . tanh(enc@W1^T + u) ----------------
// grid 1024 (64 rows each), 512 threads (8 waves = 2 wr x 4 wc).
// a-dim processed in TWO sequential halves (acc[4][4] = 64 regs live),
// epilogue consumes acc into rowp between halves -> total regs <= 128
// -> 4 waves/SIMD (2 blocks/CU) for latency hiding.
// enc K-quarter (64x256) staged in 32 KiB LDS (XOR-swizzled), staged 2x.
// W1 B-fragments read directly from global (L2-resident 2 MB).
__global__ __launch_bounds__(512, 4) void scores_kernel(
    const float* __restrict__ enc, const unsigned short* __restrict__ w1b,
    const float* __restrict__ u, const float* __restrict__ vvec,
    float* __restrict__ out) {
  __shared__ __align__(16) char encL[32768];
  __shared__ __align__(16) float sred[256];

  const int t = threadIdx.x;
  const int bid = blockIdx.x;
  const int m0 = bid * 64;
  const int b = bid >> 5; /* 32 blocks per batch (2048/64 rows) */
  const int l = t & 63, wid = t >> 6;
  const int wr = wid >> 2, wc = wid & 3;
  const int lm = l & 15, lg = l >> 4;

  const int row_a0 = wr * 32 + lm; /* a1 row is +16: same (row&7) swizzle */
  const int aswz = (row_a0 & 7) << 4;
  const int abase0 = row_a0 * 512;
  const char* w1c = (const char*)w1b;
  const int blane = (wc * 32 + lm) * 2048 + lg * 16;
  const float* ub = u + (size_t)b * 1024;

  f32x4 rowp0 = {0.f, 0.f, 0.f, 0.f}, rowp1 = {0.f, 0.f, 0.f, 0.f};

  for (int hh = 0; hh < 2; ++hh) {
    f32x4 acc[4][4];
#pragma unroll
    for (int c1 = 0; c1 < 4; ++c1)
#pragma unroll
      for (int c2 = 0; c2 < 4; ++c2) acc[c1][c2] = (f32x4){0.f, 0.f, 0.f, 0.f};

    for (int kq = 0; kq < 4; ++kq) {
      if (hh + kq) __syncthreads(); /* waves done reading prev enc quarter */
      // stage enc quarter: 64 rows x 256 k, f32 -> bf16, XOR-swizzled
#pragma unroll
      for (int it = 0; it < 4; ++it) {
        const int c = it * 512 + t;
        const int row = c >> 5;
        const int k0 = (c & 31) * 8;
        const float* g = enc + (size_t)(m0 + row) * 1024 + kq * 256 + k0;
        const float4 v0 = *(const float4*)g;
        const float4 v1 = *(const float4*)(g + 4);
        ushort8v o;
        o[0] = f2bf(v0.x); o[1] = f2bf(v0.y); o[2] = f2bf(v0.z); o[3] = f2bf(v0.w);
        o[4] = f2bf(v1.x); o[5] = f2bf(v1.y); o[6] = f2bf(v1.z); o[7] = f2bf(v1.w);
        const int dest = row * 512 + ((k0 * 2) ^ ((row & 7) << 4));
        *(ushort8v*)(encL + dest) = o;
      }
      __syncthreads(); /* enc quarter visible */

#pragma unroll
      for (int ch = 0; ch < 4; ++ch) {
        const char* wch =
            w1c + (size_t)(hh * 4 + ch) * 262144 + blane + kq * 512;
#pragma unroll
        for (int kk = 0; kk < 8; ++kk) {
          const bf16x8 b0 = *(const bf16x8*)(wch + kk * 64);
          const bf16x8 b1 = *(const bf16x8*)(wch + kk * 64 + 32768);
          const int koff = (kk * 64 + lg * 16) ^ aswz;
          const bf16x8 a0 = *(const bf16x8*)(encL + abase0 + koff);
          const bf16x8 a1 = *(const bf16x8*)(encL + abase0 + 8192 + koff);
          acc[ch][0] = __builtin_amdgcn_mfma_f32_16x16x32_bf16(a0, b0, acc[ch][0], 0, 0, 0);
          acc[ch][1] = __builtin_amdgcn_mfma_f32_16x16x32_bf16(a1, b0, acc[ch][1], 0, 0, 0);
          acc[ch][2] = __builtin_amdgcn_mfma_f32_16x16x32_bf16(a0, b1, acc[ch][2], 0, 0, 0);
          acc[ch][3] = __builtin_amdgcn_mfma_f32_16x16x32_bf16(a1, b1, acc[ch][3], 0, 0, 0);
        }
      }
    }

    // half-epilogue: tanh + v-weighted column reduction, frees acc
#pragma unroll
    for (int ch = 0; ch < 4; ++ch) {
      const int colA = (hh * 4 + ch) * 128 + wc * 32 + lm;
      const float uu0 = ub[colA], vv0 = vvec[colA];
      const float uu1 = ub[colA + 16], vv1 = vvec[colA + 16];
#pragma unroll
      for (int j = 0; j < 4; ++j) {
        rowp0[j] += ftanh(acc[ch][0][j] + uu0) * vv0;
        rowp1[j] += ftanh(acc[ch][1][j] + uu0) * vv0;
        rowp0[j] += ftanh(acc[ch][2][j] + uu1) * vv1;
        rowp1[j] += ftanh(acc[ch][3][j] + uu1) * vv1;
      }
    }
  }

  // reduce over the 16 col-lanes (lm) of each fragment group
#pragma unroll
  for (int m = 1; m < 16; m <<= 1) {
#pragma unroll
    for (int j = 0; j < 4; ++j) {
      rowp0[j] += __shfl_xor(rowp0[j], m, 64);
      rowp1[j] += __shfl_xor(rowp1[j], m, 64);
    }
  }
  if (lm == 0) {
#pragma unroll
    for (int j = 0; j < 4; ++j) {
      sred[wc * 64 + wr * 32 + lg * 4 + j] = rowp0[j];
      sred[wc * 64 + wr * 32 + 16 + lg * 4 + j] = rowp1[j];
    }
  }
  __syncthreads();
  if (t < 64) {
    out[32768 + m0 + t] =
        sred[t] + sred[64 + t] + sred[128 + t] + sred[192 + t];
  }
}

// ---------------- masked softmax over L, in place on out[32768..] --------
__global__ __launch_bounds__(256) void softmax_kernel(
    float* __restrict__ out, const int* __restrict__ mask) {
  __shared__ float wred[4];
  const int bidx = blockIdx.x;
  const int t = threadIdx.x;
  float* sc = out + 32768 + (size_t)bidx * 2048;
  const int* mk = mask + (size_t)bidx * 2048;
  const float4 s0 = *(const float4*)(sc + t * 8);
  const float4 s1 = *(const float4*)(sc + t * 8 + 4);
  const int4 q0 = *(const int4*)(mk + t * 8);
  const int4 q1 = *(const int4*)(mk + t * 8 + 4);
  float v[8] = {s0.x, s0.y, s0.z, s0.w, s1.x, s1.y, s1.z, s1.w};
  int q[8] = {q0.x, q0.y, q0.z, q0.w, q1.x, q1.y, q1.z, q1.w};
  float mx = -3.0e38f;
#pragma unroll
  for (int j = 0; j < 8; ++j) if (q[j] != 0) mx = fmaxf(mx, v[j]);
#pragma unroll
  for (int m = 1; m < 64; m <<= 1) mx = fmaxf(mx, __shfl_xor(mx, m, 64));
  if ((t & 63) == 0) wred[t >> 6] = mx;
  __syncthreads();
  mx = fmaxf(fmaxf(wred[0], wred[1]), fmaxf(wred[2], wred[3]));
  __syncthreads();
  float p[8]; float sum = 0.f;
#pragma unroll
  for (int j = 0; j < 8; ++j) {
    p[j] = (q[j] != 0) ? __expf(v[j] - mx) : 0.f;
    sum += p[j];
  }
#pragma unroll
  for (int m = 1; m < 64; m <<= 1) sum += __shfl_xor(sum, m, 64);
  if ((t & 63) == 0) wred[t >> 6] = sum;
  __syncthreads();
  sum = (wred[0] + wred[1]) + (wred[2] + wred[3]);
  const float inv = 1.0f / sum;
  const float4 o0 = {p[0] * inv, p[1] * inv, p[2] * inv, p[3] * inv};
  const float4 o1 = {p[4] * inv, p[5] * inv, p[6] * inv, p[7] * inv};
  *(float4*)(sc + t * 8) = o0;
  *(float4*)(sc + t * 8 + 4) = o1;
}

// ---------------- context[b][e] = sum_l attn[b][l] * enc[b][l][e] --------
__global__ __launch_bounds__(256) void context_kernel(
    const float* __restrict__ enc, float* __restrict__ out) {
  __shared__ __align__(16) float attnS[2048];
  __shared__ __align__(16) float red[8 * 128];
  const int bid = blockIdx.x;
  const int b = bid >> 3, ec = bid & 7;
  const int e0 = ec * 128;
  const int t = threadIdx.x;
  const float* attn = out + 32768 + (size_t)b * 2048;
#pragma unroll
  for (int i = 0; i < 8; ++i) attnS[i * 256 + t] = attn[i * 256 + t];
  __syncthreads();
  const int el = (t & 31) * 4;
  const int ls = t >> 5;
  f32x4 acc = {0.f, 0.f, 0.f, 0.f};
  const float* ebase = enc + (size_t)b * 2048 * 1024 + e0 + el;
  for (int l2 = ls; l2 < 2048; l2 += 8) {
    const float a = attnS[l2];
    const float4 ev = *(const float4*)(ebase + (size_t)l2 * 1024);
    acc[0] = fmaf(a, ev.x, acc[0]);
    acc[1] = fmaf(a, ev.y, acc[1]);
    acc[2] = fmaf(a, ev.z, acc[2]);
    acc[3] = fmaf(a, ev.w, acc[3]);
  }
  *(f32x4*)(red + ls * 128 + el) = acc;
  __syncthreads();
  if (t < 128) {
    float s = 0.f;
#pragma unroll
    for (int i = 0; i < 8; ++i) s += red[i * 128 + t];
    out[(size_t)b * 1024 + e0 + t] = s;
  }
}

extern "C" void kernel_launch(void* const* d_in, const int* in_sizes, int n_in,
                              void* d_out, int out_size, void* d_ws,
                              size_t ws_size, hipStream_t stream) {
  const float* enc = (const float*)d_in[0];
  const float* dec = (const float*)d_in[1];
  const int* mask = (const int*)d_in[2];
  const float* W1 = (const float*)d_in[3];
  const float* W2 = (const float*)d_in[4];
  const float* v = (const float*)d_in[5];
  float* out = (float*)d_out;
  char* ws = (char*)d_ws;
  unsigned short* w1b = (unsigned short*)ws; /* 2 MB bf16 W1 */
  float* u = (float*)(ws + (2u << 20));      /* 128 KB dec projection */

  w1cvt_kernel<<<512, 256, 0, stream>>>(W1, w1b);
  dec_proj_kernel<<<1024, 256, 0, stream>>>(dec, W2, u);
  scores_kernel<<<1024, 512, 0, stream>>>(enc, w1b, u, v, out);
  softmax_kernel<<<32, 256, 0, stream>>>(out, mask);
  context_kernel<<<256, 256, 0, stream>>>(enc, out);
}

// Round 5
// 430.256 us; speedup vs baseline: 1.7042x; 1.6623x over previous
//
#include <hip/hip_runtime.h>
#include <stdint.h>

typedef __bf16 bf16x8 __attribute__((ext_vector_type(8)));
typedef float f32x4 __attribute__((ext_vector_type(4)));
typedef unsigned short ushort8v __attribute__((ext_vector_type(8)));

__device__ __forceinline__ unsigned short f2bf(float f) {
  union { float f; unsigned int u; } x; x.f = f;
  unsigned int r = x.u + 0x7FFFu + ((x.u >> 16) & 1u);
  return (unsigned short)(r >> 16);
}

__device__ __forceinline__ float ftanh(float x) {
  float ax = fabsf(x);
  float e = __expf(-2.0f * ax);
  float r = (1.0f - e) / (1.0f + e);
  return copysignf(r, x);
}

// ---------------- W1 f32 -> bf16, K-quarter-major tiling ----------------
// w1b layout: [kq][a][k256]  (elem index = kq*262144 + a*256 + (k & 255))
// -> a 64-row x 256-k B-chunk is one contiguous 32 KB block.
__global__ __launch_bounds__(256) void w1cvt_kernel(
    const float* __restrict__ W1, unsigned short* __restrict__ w1b) {
  const int idx = (blockIdx.x * 256 + threadIdx.x) * 8;
  const int a = idx >> 10;
  const int k0 = idx & 1023;
  const int kq = k0 >> 8;
  const float4 v0 = *(const float4*)(W1 + idx);
  const float4 v1 = *(const float4*)(W1 + idx + 4);
  ushort8v o;
  o[0] = f2bf(v0.x); o[1] = f2bf(v0.y); o[2] = f2bf(v0.z); o[3] = f2bf(v0.w);
  o[4] = f2bf(v1.x); o[5] = f2bf(v1.y); o[6] = f2bf(v1.z); o[7] = f2bf(v1.w);
  *(ushort8v*)(w1b + kq * 262144 + a * 256 + (k0 & 255)) = o;
}

// ---------------- u[b][a] = sum_d dec[b][d] * W2[a][d] ----------------
__global__ __launch_bounds__(256) void dec_proj_kernel(
    const float* __restrict__ dec, const float* __restrict__ W2,
    float* __restrict__ u) {
  __shared__ __align__(16) float w2s[1024];
  const int a = blockIdx.x;
  const int t = threadIdx.x;
  *(float4*)(w2s + t * 4) = *(const float4*)(W2 + (size_t)a * 1024 + t * 4);
  __syncthreads();
  const int wid = t >> 6, l = t & 63;
  for (int bi = 0; bi < 8; ++bi) {
    const int b = wid * 8 + bi;
    const float* dp = dec + (size_t)b * 1024;
    float acc = 0.f;
#pragma unroll
    for (int i = 0; i < 4; ++i) {
      const int k = i * 256 + l * 4;
      const float4 dv = *(const float4*)(dp + k);
      const float4 wv = *(const float4*)(w2s + k);
      acc = fmaf(dv.x, wv.x, acc); acc = fmaf(dv.y, wv.y, acc);
      acc = fmaf(dv.z, wv.z, acc); acc = fmaf(dv.w, wv.w, acc);
    }
#pragma unroll
    for (int m = 1; m < 64; m <<= 1) acc += __shfl_xor(acc, m, 64);
    if (l == 0) u[(size_t)b * 1024 + a] = acc;
  }
}

// ---------------- fused scores: v . tanh(enc@W1^T + u) ----------------
// grid 1024 (64 rows each), 512 threads (8 waves = 2 wr x 4 wc).
// Per (kq, c8) phase: cooperative burst-load of a contiguous 32 KB W1
// chunk (64 a x 256 k) into XOR-swizzled LDS (reg-staged ds_write);
// inner kk loop is pure LDS + MFMA (no global access).
// LDS: enc 32K + B 32K + sred 1K = 66 KB -> 2 blocks/CU, waves=4.
__global__ __launch_bounds__(512, 4) void scores_kernel(
    const float* __restrict__ enc, const unsigned short* __restrict__ w1b,
    const float* __restrict__ u, const float* __restrict__ vvec,
    float* __restrict__ out) {
  __shared__ __align__(16) char encL[32768];
  __shared__ __align__(16) char Bl[32768];
  __shared__ __align__(16) float sred[256];

  const int t = threadIdx.x;
  const int bid = blockIdx.x;
  const int m0 = bid * 64;
  const int b = bid >> 5; /* 32 blocks per batch (2048/64 rows) */
  const int l = t & 63, wid = t >> 6;
  const int wr = wid >> 2, wc = wid & 3;
  const int lm = l & 15, lg = l >> 4;

  const int row_a0 = wr * 32 + lm; /* rowfrag1 is +16: same (row&7) bits */
  const int aswz = (row_a0 & 7) << 4;
  const int abase0 = row_a0 * 512;
  const char* w1c = (const char*)w1b;
  const float* ub = u + (size_t)b * 1024;

  // B-stage: thread handles chunk-linear 16B pieces f = i*8192 + t*16;
  // swizzled dest = row*512 + ((f&511) ^ ((row&7)<<4)), row = f>>9.
  int bdst[4];
#pragma unroll
  for (int i = 0; i < 4; ++i) {
    const int f = i * 8192 + t * 16;
    const int row = f >> 9;
    bdst[i] = row * 512 + ((f & 511) ^ ((row & 7) << 4));
  }
  // b-frag read address (consumer): row brow = wc*16+lm
  const int brow = wc * 16 + lm;
  const int bswz = (brow & 7) << 4;
  const int bbase = brow * 512;

  f32x4 rowp0 = {0.f, 0.f, 0.f, 0.f}, rowp1 = {0.f, 0.f, 0.f, 0.f};

  for (int hh = 0; hh < 2; ++hh) {
    f32x4 acc[8][2];
#pragma unroll
    for (int c1 = 0; c1 < 8; ++c1)
#pragma unroll
      for (int c2 = 0; c2 < 2; ++c2) acc[c1][c2] = (f32x4){0.f, 0.f, 0.f, 0.f};

    for (int kq = 0; kq < 4; ++kq) {
      // ---- stage enc quarter: 64 rows x 256 k, f32 -> bf16, swizzled ----
      // (previous phase ended with __syncthreads: encL free to overwrite)
#pragma unroll
      for (int it = 0; it < 4; ++it) {
        const int c = it * 512 + t;
        const int row = c >> 5;
        const int k0 = (c & 31) * 8;
        const float* g = enc + (size_t)(m0 + row) * 1024 + kq * 256 + k0;
        const float4 v0 = *(const float4*)g;
        const float4 v1 = *(const float4*)(g + 4);
        ushort8v o;
        o[0] = f2bf(v0.x); o[1] = f2bf(v0.y); o[2] = f2bf(v0.z); o[3] = f2bf(v0.w);
        o[4] = f2bf(v1.x); o[5] = f2bf(v1.y); o[6] = f2bf(v1.z); o[7] = f2bf(v1.w);
        const int dest = row * 512 + ((k0 * 2) ^ ((row & 7) << 4));
        *(ushort8v*)(encL + dest) = o;
      }

      const char* qbase = w1c + (size_t)kq * 524288 + (size_t)hh * 262144;
#pragma unroll
      for (int c8 = 0; c8 < 8; ++c8) {
        // ---- stage B chunk: contiguous 32 KB, swizzled reg->LDS ----
        const char* cb = qbase + (size_t)c8 * 32768;
        const bf16x8 s0 = *(const bf16x8*)(cb + 0 * 8192 + t * 16);
        const bf16x8 s1 = *(const bf16x8*)(cb + 1 * 8192 + t * 16);
        const bf16x8 s2 = *(const bf16x8*)(cb + 2 * 8192 + t * 16);
        const bf16x8 s3 = *(const bf16x8*)(cb + 3 * 8192 + t * 16);
        *(bf16x8*)(Bl + bdst[0]) = s0;
        *(bf16x8*)(Bl + bdst[1]) = s1;
        *(bf16x8*)(Bl + bdst[2]) = s2;
        *(bf16x8*)(Bl + bdst[3]) = s3;
        __syncthreads(); /* B chunk (+ enc quarter at c8==0) visible */
#pragma unroll
        for (int kk = 0; kk < 8; ++kk) {
          const int koff = (kk * 64 + lg * 16) ^ aswz;
          const bf16x8 a0 = *(const bf16x8*)(encL + abase0 + koff);
          const bf16x8 a1 = *(const bf16x8*)(encL + abase0 + 8192 + koff);
          const bf16x8 b0 =
              *(const bf16x8*)(Bl + bbase + ((kk * 64 + lg * 16) ^ bswz));
          acc[c8][0] = __builtin_amdgcn_mfma_f32_16x16x32_bf16(a0, b0, acc[c8][0], 0, 0, 0);
          acc[c8][1] = __builtin_amdgcn_mfma_f32_16x16x32_bf16(a1, b0, acc[c8][1], 0, 0, 0);
        }
        __syncthreads(); /* compute done: Bl (and encL at c8==7) free */
      }
    }

    // half-epilogue: tanh + v-weighted column reduction, frees acc
#pragma unroll
    for (int c8 = 0; c8 < 8; ++c8) {
      const int colA = hh * 512 + c8 * 64 + wc * 16 + lm;
      const float uu = ub[colA], vv = vvec[colA];
#pragma unroll
      for (int j = 0; j < 4; ++j) {
        rowp0[j] += ftanh(acc[c8][0][j] + uu) * vv;
        rowp1[j] += ftanh(acc[c8][1][j] + uu) * vv;
      }
    }
  }

  // reduce over the 16 col-lanes (lm) of each fragment group
#pragma unroll
  for (int m = 1; m < 16; m <<= 1) {
#pragma unroll
    for (int j = 0; j < 4; ++j) {
      rowp0[j] += __shfl_xor(rowp0[j], m, 64);
      rowp1[j] += __shfl_xor(rowp1[j], m, 64);
    }
  }
  if (lm == 0) {
#pragma unroll
    for (int j = 0; j < 4; ++j) {
      sred[wc * 64 + wr * 32 + lg * 4 + j] = rowp0[j];
      sred[wc * 64 + wr * 32 + 16 + lg * 4 + j] = rowp1[j];
    }
  }
  __syncthreads();
  if (t < 64) {
    out[32768 + m0 + t] =
        sred[t] + sred[64 + t] + sred[128 + t] + sred[192 + t];
  }
}

// ---------------- masked softmax over L, in place on out[32768..] --------
__global__ __launch_bounds__(256) void softmax_kernel(
    float* __restrict__ out, const int* __restrict__ mask) {
  __shared__ float wred[4];
  const int bidx = blockIdx.x;
  const int t = threadIdx.x;
  float* sc = out + 32768 + (size_t)bidx * 2048;
  const int* mk = mask + (size_t)bidx * 2048;
  const float4 s0 = *(const float4*)(sc + t * 8);
  const float4 s1 = *(const float4*)(sc + t * 8 + 4);
  const int4 q0 = *(const int4*)(mk + t * 8);
  const int4 q1 = *(const int4*)(mk + t * 8 + 4);
  float v[8] = {s0.x, s0.y, s0.z, s0.w, s1.x, s1.y, s1.z, s1.w};
  int q[8] = {q0.x, q0.y, q0.z, q0.w, q1.x, q1.y, q1.z, q1.w};
  float mx = -3.0e38f;
#pragma unroll
  for (int j = 0; j < 8; ++j) if (q[j] != 0) mx = fmaxf(mx, v[j]);
#pragma unroll
  for (int m = 1; m < 64; m <<= 1) mx = fmaxf(mx, __shfl_xor(mx, m, 64));
  if ((t & 63) == 0) wred[t >> 6] = mx;
  __syncthreads();
  mx = fmaxf(fmaxf(wred[0], wred[1]), fmaxf(wred[2], wred[3]));
  __syncthreads();
  float p[8]; float sum = 0.f;
#pragma unroll
  for (int j = 0; j < 8; ++j) {
    p[j] = (q[j] != 0) ? __expf(v[j] - mx) : 0.f;
    sum += p[j];
  }
#pragma unroll
  for (int m = 1; m < 64; m <<= 1) sum += __shfl_xor(sum, m, 64);
  if ((t & 63) == 0) wred[t >> 6] = sum;
  __syncthreads();
  sum = (wred[0] + wred[1]) + (wred[2] + wred[3]);
  const float inv = 1.0f / sum;
  const float4 o0 = {p[0] * inv, p[1] * inv, p[2] * inv, p[3] * inv};
  const float4 o1 = {p[4] * inv, p[5] * inv, p[6] * inv, p[7] * inv};
  *(float4*)(sc + t * 8) = o0;
  *(float4*)(sc + t * 8 + 4) = o1;
}

// ---------------- context[b][e] = sum_l attn[b][l] * enc[b][l][e] --------
__global__ __launch_bounds__(256) void context_kernel(
    const float* __restrict__ enc, float* __restrict__ out) {
  __shared__ __align__(16) float attnS[2048];
  __shared__ __align__(16) float red[8 * 128];
  const int bid = blockIdx.x;
  const int b = bid >> 3, ec = bid & 7;
  const int e0 = ec * 128;
  const int t = threadIdx.x;
  const float* attn = out + 32768 + (size_t)b * 2048;
#pragma unroll
  for (int i = 0; i < 8; ++i) attnS[i * 256 + t] = attn[i * 256 + t];
  __syncthreads();
  const int el = (t & 31) * 4;
  const int ls = t >> 5;
  f32x4 acc = {0.f, 0.f, 0.f, 0.f};
  const float* ebase = enc + (size_t)b * 2048 * 1024 + e0 + el;
  for (int l2 = ls; l2 < 2048; l2 += 8) {
    const float a = attnS[l2];
    const float4 ev = *(const float4*)(ebase + (size_t)l2 * 1024);
    acc[0] = fmaf(a, ev.x, acc[0]);
    acc[1] = fmaf(a, ev.y, acc[1]);
    acc[2] = fmaf(a, ev.z, acc[2]);
    acc[3] = fmaf(a, ev.w, acc[3]);
  }
  *(f32x4*)(red + ls * 128 + el) = acc;
  __syncthreads();
  if (t < 128) {
    float s = 0.f;
#pragma unroll
    for (int i = 0; i < 8; ++i) s += red[i * 128 + t];
    out[(size_t)b * 1024 + e0 + t] = s;
  }
}

extern "C" void kernel_launch(void* const* d_in, const int* in_sizes, int n_in,
                              void* d_out, int out_size, void* d_ws,
                              size_t ws_size, hipStream_t stream) {
  const float* enc = (const float*)d_in[0];
  const float* dec = (const float*)d_in[1];
  const int* mask = (const int*)d_in[2];
  const float* W1 = (const float*)d_in[3];
  const float* W2 = (const float*)d_in[4];
  const float* v = (const float*)d_in[5];
  float* out = (float*)d_out;
  char* ws = (char*)d_ws;
  unsigned short* w1b = (unsigned short*)ws; /* 2 MB bf16 W1 (kq-tiled) */
  float* u = (float*)(ws + (2u << 20));      /* 128 KB dec projection */

  w1cvt_kernel<<<512, 256, 0, stream>>>(W1, w1b);
  dec_proj_kernel<<<1024, 256, 0, stream>>>(dec, W2, u);
  scores_kernel<<<1024, 512, 0, stream>>>(enc, w1b, u, v, out);
  softmax_kernel<<<32, 256, 0, stream>>>(out, mask);
  context_kernel<<<256, 256, 0, stream>>>(enc, out);
}

// Round 6
// 373.646 us; speedup vs baseline: 1.9623x; 1.1515x over previous
//
#include <hip/hip_runtime.h>
#include <stdint.h>

typedef __bf16 bf16x8 __attribute__((ext_vector_type(8)));
typedef float f32x4 __attribute__((ext_vector_type(4)));
typedef unsigned short ushort8v __attribute__((ext_vector_type(8)));

__device__ __forceinline__ unsigned short f2bf(float f) {
  union { float f; unsigned int u; } x; x.f = f;
  unsigned int r = x.u + 0x7FFFu + ((x.u >> 16) & 1u);
  return (unsigned short)(r >> 16);
}

__device__ __forceinline__ float ftanh(float x) {
  float ax = fabsf(x);
  float e = __expf(-2.0f * ax);
  float r = (1.0f - e) / (1.0f + e);
  return copysignf(r, x);
}

// ---------------- W1 f32 -> bf16, K-quarter-major tiling ----------------
// w1b layout: [kq][a][k256]  (elem index = kq*262144 + a*256 + (k & 255))
__global__ __launch_bounds__(256) void w1cvt_kernel(
    const float* __restrict__ W1, unsigned short* __restrict__ w1b) {
  const int idx = (blockIdx.x * 256 + threadIdx.x) * 8;
  const int a = idx >> 10;
  const int k0 = idx & 1023;
  const int kq = k0 >> 8;
  const float4 v0 = *(const float4*)(W1 + idx);
  const float4 v1 = *(const float4*)(W1 + idx + 4);
  ushort8v o;
  o[0] = f2bf(v0.x); o[1] = f2bf(v0.y); o[2] = f2bf(v0.z); o[3] = f2bf(v0.w);
  o[4] = f2bf(v1.x); o[5] = f2bf(v1.y); o[6] = f2bf(v1.z); o[7] = f2bf(v1.w);
  *(ushort8v*)(w1b + kq * 262144 + a * 256 + (k0 & 255)) = o;
}

// ---------------- u[b][a] = sum_d dec[b][d] * W2[a][d] ----------------
__global__ __launch_bounds__(256) void dec_proj_kernel(
    const float* __restrict__ dec, const float* __restrict__ W2,
    float* __restrict__ u) {
  __shared__ __align__(16) float w2s[1024];
  const int a = blockIdx.x;
  const int t = threadIdx.x;
  *(float4*)(w2s + t * 4) = *(const float4*)(W2 + (size_t)a * 1024 + t * 4);
  __syncthreads();
  const int wid = t >> 6, l = t & 63;
  for (int bi = 0; bi < 8; ++bi) {
    const int b = wid * 8 + bi;
    const float* dp = dec + (size_t)b * 1024;
    float acc = 0.f;
#pragma unroll
    for (int i = 0; i < 4; ++i) {
      const int k = i * 256 + l * 4;
      const float4 dv = *(const float4*)(dp + k);
      const float4 wv = *(const float4*)(w2s + k);
      acc = fmaf(dv.x, wv.x, acc); acc = fmaf(dv.y, wv.y, acc);
      acc = fmaf(dv.z, wv.z, acc); acc = fmaf(dv.w, wv.w, acc);
    }
#pragma unroll
    for (int m = 1; m < 64; m <<= 1) acc += __shfl_xor(acc, m, 64);
    if (l == 0) u[(size_t)b * 1024 + a] = acc;
  }
}

// ---------------- fused scores: v . tanh(enc@W1^T + u) ----------------
// grid 1024 (64 rows each), 512 threads (8 waves = 2 wr x 4 wc).
// A-fragments held in REGISTERS across the col-chunk loop (read 1x/kq);
// B chunks (64 a-cols x 256 k = 32 KB) double-buffered in LDS, single
// barrier per phase, issue-early/write-late staging (T14).
// Swizzle (row&15)<<4: 16-lane b128 phase groups hit 16 distinct slots.
// LDS: enc 32K + B 2x32K + sred 1K = 97 KB -> 1 block/CU, 2 waves/SIMD.
__global__ __launch_bounds__(512, 2) void scores_kernel(
    const float* __restrict__ enc, const unsigned short* __restrict__ w1b,
    const float* __restrict__ u, const float* __restrict__ vvec,
    float* __restrict__ out) {
  __shared__ __align__(16) char encL[32768];
  __shared__ __align__(16) char Bl[65536];
  __shared__ __align__(16) float sred[256];

  const int t = threadIdx.x;
  const int bid = blockIdx.x;
  const int m0 = bid * 64;
  const int b = bid >> 5; /* 32 blocks per batch (2048/64 rows) */
  const int l = t & 63, wid = t >> 6;
  const int wr = wid >> 2, wc = wid & 3;
  const int lm = l & 15, lg = l >> 4;

  const int row_a0 = wr * 32 + lm; /* rowfrag1 = +16: same (row&15) bits */
  const int aswz = lm << 4;        /* (row_a0 & 15) << 4 */
  const int abase0 = row_a0 * 512;
  const char* w1c = (const char*)w1b;
  const float* ub = u + (size_t)b * 1024;

  // B-stage dest offsets: piece f = i*8192 + t*16, row = f>>9,
  // dest = row*512 + ((f&511) ^ ((row&15)<<4))
  int bdst[4];
#pragma unroll
  for (int i = 0; i < 4; ++i) {
    const int f = i * 8192 + t * 16;
    const int row = f >> 9;
    bdst[i] = row * 512 + ((f & 511) ^ ((row & 15) << 4));
  }
  // b-frag read base: row brow = wc*16 + lm
  const int bbase = (wc * 16 + lm) * 512;
  const int bswz = lm << 4; /* (brow & 15) << 4 */

  f32x4 rowp0 = {0.f, 0.f, 0.f, 0.f}, rowp1 = {0.f, 0.f, 0.f, 0.f};

  // prologue: stage B chunk for phase 0 (written to Bl[0]; the barrier
  // after the first enc staging makes it visible)
  {
    const char* cb = w1c; /* phase 0: kq=0, a0=0 */
    const bf16x8 s0 = *(const bf16x8*)(cb + 0 * 8192 + t * 16);
    const bf16x8 s1 = *(const bf16x8*)(cb + 1 * 8192 + t * 16);
    const bf16x8 s2 = *(const bf16x8*)(cb + 2 * 8192 + t * 16);
    const bf16x8 s3 = *(const bf16x8*)(cb + 3 * 8192 + t * 16);
    *(bf16x8*)(Bl + bdst[0]) = s0;
    *(bf16x8*)(Bl + bdst[1]) = s1;
    *(bf16x8*)(Bl + bdst[2]) = s2;
    *(bf16x8*)(Bl + bdst[3]) = s3;
  }

  int p = 0; /* global phase = hh*32 + kq*8 + c8 */
  for (int hh = 0; hh < 2; ++hh) {
    f32x4 acc[8][2];
#pragma unroll
    for (int c1 = 0; c1 < 8; ++c1)
#pragma unroll
      for (int c2 = 0; c2 < 2; ++c2) acc[c1][c2] = (f32x4){0.f, 0.f, 0.f, 0.f};

    for (int kq = 0; kq < 4; ++kq) {
      // ---- stage enc quarter: 64 rows x 256 k, f32 -> bf16, swizzled ----
      // (phase-end barrier of the previous phase guards encL reuse)
#pragma unroll
      for (int it = 0; it < 4; ++it) {
        const int c = it * 512 + t;
        const int row = c >> 5;
        const int k0 = (c & 31) * 8;
        const float* g = enc + (size_t)(m0 + row) * 1024 + kq * 256 + k0;
        const float4 v0 = *(const float4*)g;
        const float4 v1 = *(const float4*)(g + 4);
        ushort8v o;
        o[0] = f2bf(v0.x); o[1] = f2bf(v0.y); o[2] = f2bf(v0.z); o[3] = f2bf(v0.w);
        o[4] = f2bf(v1.x); o[5] = f2bf(v1.y); o[6] = f2bf(v1.z); o[7] = f2bf(v1.w);
        const int dest = row * 512 + ((k0 * 2) ^ ((row & 15) << 4));
        *(ushort8v*)(encL + dest) = o;
      }
      __syncthreads(); /* enc + pending B writes visible */

      // ---- A-fragments into registers: 16 x ds_read_b128, once per kq ----
      bf16x8 af[2][8];
#pragma unroll
      for (int rf = 0; rf < 2; ++rf)
#pragma unroll
        for (int kk = 0; kk < 8; ++kk)
          af[rf][kk] = *(const bf16x8*)(encL + abase0 + rf * 8192 +
                                        ((kk * 64 + lg * 16) ^ aswz));

#pragma unroll
      for (int c8 = 0; c8 < 8; ++c8) {
        // issue-early: global loads for chunk p+1 (L2-resident W1)
        bf16x8 s0, s1, s2, s3;
        const int p1 = p + 1;
        if (p1 < 64) {
          const char* cb = w1c + (size_t)((p1 >> 3) & 3) * 524288 +
                           (size_t)(((p1 >> 5) * 512) + (p1 & 7) * 64) * 512;
          s0 = *(const bf16x8*)(cb + 0 * 8192 + t * 16);
          s1 = *(const bf16x8*)(cb + 1 * 8192 + t * 16);
          s2 = *(const bf16x8*)(cb + 2 * 8192 + t * 16);
          s3 = *(const bf16x8*)(cb + 3 * 8192 + t * 16);
        }
        // compute phase p: 8 b-reads + 16 MFMA (A from registers)
        const int buf = (p & 1) * 32768;
#pragma unroll
        for (int kk = 0; kk < 8; ++kk) {
          const bf16x8 b0 =
              *(const bf16x8*)(Bl + buf + bbase + ((kk * 64 + lg * 16) ^ bswz));
          acc[c8][0] = __builtin_amdgcn_mfma_f32_16x16x32_bf16(af[0][kk], b0, acc[c8][0], 0, 0, 0);
          acc[c8][1] = __builtin_amdgcn_mfma_f32_16x16x32_bf16(af[1][kk], b0, acc[c8][1], 0, 0, 0);
        }
        // write-late: stage chunk p+1 into the other buffer
        if (p1 < 64) {
          const int nbuf = (p1 & 1) * 32768;
          *(bf16x8*)(Bl + nbuf + bdst[0]) = s0;
          *(bf16x8*)(Bl + nbuf + bdst[1]) = s1;
          *(bf16x8*)(Bl + nbuf + bdst[2]) = s2;
          *(bf16x8*)(Bl + nbuf + bdst[3]) = s3;
        }
        __syncthreads(); /* B[p+1] visible; encL/B[p] free for reuse */
        ++p;
      }
    }

    // half-epilogue: tanh + v-weighted column reduction, frees acc
#pragma unroll
    for (int c8 = 0; c8 < 8; ++c8) {
      const int colA = hh * 512 + c8 * 64 + wc * 16 + lm;
      const float uu = ub[colA], vv = vvec[colA];
#pragma unroll
      for (int j = 0; j < 4; ++j) {
        rowp0[j] += ftanh(acc[c8][0][j] + uu) * vv;
        rowp1[j] += ftanh(acc[c8][1][j] + uu) * vv;
      }
    }
  }

  // reduce over the 16 col-lanes (lm) of each fragment group
#pragma unroll
  for (int m = 1; m < 16; m <<= 1) {
#pragma unroll
    for (int j = 0; j < 4; ++j) {
      rowp0[j] += __shfl_xor(rowp0[j], m, 64);
      rowp1[j] += __shfl_xor(rowp1[j], m, 64);
    }
  }
  if (lm == 0) {
#pragma unroll
    for (int j = 0; j < 4; ++j) {
      sred[wc * 64 + wr * 32 + lg * 4 + j] = rowp0[j];
      sred[wc * 64 + wr * 32 + 16 + lg * 4 + j] = rowp1[j];
    }
  }
  __syncthreads();
  if (t < 64) {
    out[32768 + m0 + t] =
        sred[t] + sred[64 + t] + sred[128 + t] + sred[192 + t];
  }
}

// ---------------- masked softmax over L, in place on out[32768..] --------
__global__ __launch_bounds__(256) void softmax_kernel(
    float* __restrict__ out, const int* __restrict__ mask) {
  __shared__ float wred[4];
  const int bidx = blockIdx.x;
  const int t = threadIdx.x;
  float* sc = out + 32768 + (size_t)bidx * 2048;
  const int* mk = mask + (size_t)bidx * 2048;
  const float4 s0 = *(const float4*)(sc + t * 8);
  const float4 s1 = *(const float4*)(sc + t * 8 + 4);
  const int4 q0 = *(const int4*)(mk + t * 8);
  const int4 q1 = *(const int4*)(mk + t * 8 + 4);
  float v[8] = {s0.x, s0.y, s0.z, s0.w, s1.x, s1.y, s1.z, s1.w};
  int q[8] = {q0.x, q0.y, q0.z, q0.w, q1.x, q1.y, q1.z, q1.w};
  float mx = -3.0e38f;
#pragma unroll
  for (int j = 0; j < 8; ++j) if (q[j] != 0) mx = fmaxf(mx, v[j]);
#pragma unroll
  for (int m = 1; m < 64; m <<= 1) mx = fmaxf(mx, __shfl_xor(mx, m, 64));
  if ((t & 63) == 0) wred[t >> 6] = mx;
  __syncthreads();
  mx = fmaxf(fmaxf(wred[0], wred[1]), fmaxf(wred[2], wred[3]));
  __syncthreads();
  float p[8]; float sum = 0.f;
#pragma unroll
  for (int j = 0; j < 8; ++j) {
    p[j] = (q[j] != 0) ? __expf(v[j] - mx) : 0.f;
    sum += p[j];
  }
#pragma unroll
  for (int m = 1; m < 64; m <<= 1) sum += __shfl_xor(sum, m, 64);
  if ((t & 63) == 0) wred[t >> 6] = sum;
  __syncthreads();
  sum = (wred[0] + wred[1]) + (wred[2] + wred[3]);
  const float inv = 1.0f / sum;
  const float4 o0 = {p[0] * inv, p[1] * inv, p[2] * inv, p[3] * inv};
  const float4 o1 = {p[4] * inv, p[5] * inv, p[6] * inv, p[7] * inv};
  *(float4*)(sc + t * 8) = o0;
  *(float4*)(sc + t * 8 + 4) = o1;
}

// ---------------- context[b][e] = sum_l attn[b][l] * enc[b][l][e] --------
__global__ __launch_bounds__(256) void context_kernel(
    const float* __restrict__ enc, float* __restrict__ out) {
  __shared__ __align__(16) float attnS[2048];
  __shared__ __align__(16) float red[8 * 128];
  const int bid = blockIdx.x;
  const int b = bid >> 3, ec = bid & 7;
  const int e0 = ec * 128;
  const int t = threadIdx.x;
  const float* attn = out + 32768 + (size_t)b * 2048;
#pragma unroll
  for (int i = 0; i < 8; ++i) attnS[i * 256 + t] = attn[i * 256 + t];
  __syncthreads();
  const int el = (t & 31) * 4;
  const int ls = t >> 5;
  f32x4 acc = {0.f, 0.f, 0.f, 0.f};
  const float* ebase = enc + (size_t)b * 2048 * 1024 + e0 + el;
  for (int l2 = ls; l2 < 2048; l2 += 8) {
    const float a = attnS[l2];
    const float4 ev = *(const float4*)(ebase + (size_t)l2 * 1024);
    acc[0] = fmaf(a, ev.x, acc[0]);
    acc[1] = fmaf(a, ev.y, acc[1]);
    acc[2] = fmaf(a, ev.z, acc[2]);
    acc[3] = fmaf(a, ev.w, acc[3]);
  }
  *(f32x4*)(red + ls * 128 + el) = acc;
  __syncthreads();
  if (t < 128) {
    float s = 0.f;
#pragma unroll
    for (int i = 0; i < 8; ++i) s += red[i * 128 + t];
    out[(size_t)b * 1024 + e0 + t] = s;
  }
}

extern "C" void kernel_launch(void* const* d_in, const int* in_sizes, int n_in,
                              void* d_out, int out_size, void* d_ws,
                              size_t ws_size, hipStream_t stream) {
  const float* enc = (const float*)d_in[0];
  const float* dec = (const float*)d_in[1];
  const int* mask = (const int*)d_in[2];
  const float* W1 = (const float*)d_in[3];
  const float* W2 = (const float*)d_in[4];
  const float* v = (const float*)d_in[5];
  float* out = (float*)d_out;
  char* ws = (char*)d_ws;
  unsigned short* w1b = (unsigned short*)ws; /* 2 MB bf16 W1 (kq-tiled) */
  float* u = (float*)(ws + (2u << 20));      /* 128 KB dec projection */

  w1cvt_kernel<<<512, 256, 0, stream>>>(W1, w1b);
  dec_proj_kernel<<<1024, 256, 0, stream>>>(dec, W2, u);
  scores_kernel<<<1024, 512, 0, stream>>>(enc, w1b, u, v, out);
  softmax_kernel<<<32, 256, 0, stream>>>(out, mask);
  context_kernel<<<256, 256, 0, stream>>>(enc, out);
}

// Round 7
// 336.085 us; speedup vs baseline: 2.1817x; 1.1118x over previous
//
#include <hip/hip_runtime.h>
#include <stdint.h>

typedef __bf16 bf16x8 __attribute__((ext_vector_type(8)));
typedef float f32x4 __attribute__((ext_vector_type(4)));
typedef unsigned short ushort8v __attribute__((ext_vector_type(8)));

__device__ __forceinline__ void gload_lds16(const void* g, void* l) {
  __builtin_amdgcn_global_load_lds(
      (const __attribute__((address_space(1))) void*)g,
      (__attribute__((address_space(3))) void*)l, 16, 0, 0);
}

__device__ __forceinline__ unsigned short f2bf(float f) {
  union { float f; unsigned int u; } x; x.f = f;
  unsigned int r = x.u + 0x7FFFu + ((x.u >> 16) & 1u);
  return (unsigned short)(r >> 16);
}

__device__ __forceinline__ float ftanh(float x) {
  float ax = fabsf(x);
  float e = __expf(-2.0f * ax);
  float r = (1.0f - e) / (1.0f + e);
  return copysignf(r, x);
}

// -------- W1 f32 -> bf16, PRE-SWIZZLED 16 KB chunk layout --------
// chunk p (p = ((hh*4+kq)*8+c8)*2+kh) covers a in [hh*512+c8*64, +64),
// k in [kq*256+kh*128, +128). Within a chunk, dest byte d holds source
// k-offset (d&255) ^ ((row&15)<<4), row = d>>8  (inverse of read swizzle),
// so a LINEAR global->LDS copy + swizzled ds_read yields correct frags.
__global__ __launch_bounds__(256) void w1cvt_kernel(
    const float* __restrict__ W1, unsigned short* __restrict__ w1b) {
  const int g = blockIdx.x * 256 + threadIdx.x; /* 16-B piece id */
  const int p = g >> 10;
  const int q = g & 1023;
  const int row = q >> 4;
  const int off = (q & 15) * 16;
  const int srcoff = off ^ ((row & 15) << 4);
  const int kh = p & 1, c8 = (p >> 1) & 7, kq = (p >> 4) & 3, hh = p >> 6;
  const int a = hh * 512 + c8 * 64 + row;
  const int k = kq * 256 + kh * 128 + (srcoff >> 1);
  const float* src = W1 + (size_t)a * 1024 + k;
  const float4 v0 = *(const float4*)src;
  const float4 v1 = *(const float4*)(src + 4);
  ushort8v o;
  o[0] = f2bf(v0.x); o[1] = f2bf(v0.y); o[2] = f2bf(v0.z); o[3] = f2bf(v0.w);
  o[4] = f2bf(v1.x); o[5] = f2bf(v1.y); o[6] = f2bf(v1.z); o[7] = f2bf(v1.w);
  *((ushort8v*)w1b + g) = o;
}

// ---------------- u[b][a] = sum_d dec[b][d] * W2[a][d] ----------------
__global__ __launch_bounds__(256) void dec_proj_kernel(
    const float* __restrict__ dec, const float* __restrict__ W2,
    float* __restrict__ u) {
  __shared__ __align__(16) float w2s[1024];
  const int a = blockIdx.x;
  const int t = threadIdx.x;
  *(float4*)(w2s + t * 4) = *(const float4*)(W2 + (size_t)a * 1024 + t * 4);
  __syncthreads();
  const int wid = t >> 6, l = t & 63;
  for (int bi = 0; bi < 8; ++bi) {
    const int b = wid * 8 + bi;
    const float* dp = dec + (size_t)b * 1024;
    float acc = 0.f;
#pragma unroll
    for (int i = 0; i < 4; ++i) {
      const int k = i * 256 + l * 4;
      const float4 dv = *(const float4*)(dp + k);
      const float4 wv = *(const float4*)(w2s + k);
      acc = fmaf(dv.x, wv.x, acc); acc = fmaf(dv.y, wv.y, acc);
      acc = fmaf(dv.z, wv.z, acc); acc = fmaf(dv.w, wv.w, acc);
    }
#pragma unroll
    for (int m = 1; m < 64; m <<= 1) acc += __shfl_xor(acc, m, 64);
    if (l == 0) u[(size_t)b * 1024 + a] = acc;
  }
}

// ---------------- fused scores: v . tanh(enc@W1^T + u) ----------------
// grid 1024 (64 rows each), 512 threads (8 waves = 2 wr x 4 wc).
// B: 16 KB chunks (64a x 128k) double-buffered via global_load_lds from
// the pre-swizzled w1b (linear copy, swizzled read). Buffer parity = kh.
// enc: 64x256 K-quarter in 32 KB LDS, XOR-swizzled, reg-staged.
// LDS 65 KB -> 2 blocks/CU (m114 overlap); acc[8][2] in AGPRs.
__global__ __launch_bounds__(512, 4) void scores_kernel(
    const float* __restrict__ enc, const unsigned short* __restrict__ w1b,
    const float* __restrict__ u, const float* __restrict__ vvec,
    float* __restrict__ out) {
  __shared__ __align__(16) char encL[32768];
  __shared__ __align__(16) char Bl[32768];
  __shared__ __align__(16) float sred[256];

  const int t = threadIdx.x;
  const int bid = blockIdx.x;
  const int m0 = bid * 64;
  const int b = bid >> 5; /* 32 blocks per batch (2048/64 rows) */
  const int l = t & 63, wid = t >> 6;
  const int wr = wid >> 2, wc = wid & 3;
  const int lm = l & 15, lg = l >> 4;

  const int row_a0 = wr * 32 + lm; /* rowfrag1 = +16: same (row&15) bits */
  const int aswz = lm << 4;        /* (row_a0 & 15) << 4 */
  const int abase0 = row_a0 * 512;
  const int bbase = (wc * 16 + lm) * 256; /* B row stride = 256 B */
  const int bswz = lm << 4;
  const char* w1c = (const char*)w1b;
  const float* ub = u + (size_t)b * 1024;

  // stage addressing: wave wid covers dest bytes [wid*2048, +2048)
  const int sbase0 = wid * 2048;
  const int sbase1 = wid * 2048 + 1024;
  const int glane = l * 16;

  f32x4 rowp0 = {0.f, 0.f, 0.f, 0.f}, rowp1 = {0.f, 0.f, 0.f, 0.f};

  // prologue: stage chunk 0 into buffer 0
  gload_lds16(w1c + sbase0 + glane, Bl + sbase0);
  gload_lds16(w1c + sbase1 + glane, Bl + sbase1);

  int p = 0; /* global phase/chunk = ((hh*4+kq)*8+c8)*2+kh */
  for (int hh = 0; hh < 2; ++hh) {
    f32x4 acc[8][2];
#pragma unroll
    for (int c1 = 0; c1 < 8; ++c1)
#pragma unroll
      for (int c2 = 0; c2 < 2; ++c2) acc[c1][c2] = (f32x4){0.f, 0.f, 0.f, 0.f};

    for (int kq = 0; kq < 4; ++kq) {
      // ---- stage enc quarter: 64 rows x 256 k, f32 -> bf16, swizzled ----
      // (previous phase-end barrier guarantees old encL reads are done)
#pragma unroll
      for (int it = 0; it < 4; ++it) {
        const int c = it * 512 + t;
        const int row = c >> 5;
        const int k0 = (c & 31) * 8;
        const float* g = enc + (size_t)(m0 + row) * 1024 + kq * 256 + k0;
        const float4 v0 = *(const float4*)g;
        const float4 v1 = *(const float4*)(g + 4);
        ushort8v o;
        o[0] = f2bf(v0.x); o[1] = f2bf(v0.y); o[2] = f2bf(v0.z); o[3] = f2bf(v0.w);
        o[4] = f2bf(v1.x); o[5] = f2bf(v1.y); o[6] = f2bf(v1.z); o[7] = f2bf(v1.w);
        const int dest = row * 512 + ((k0 * 2) ^ ((row & 15) << 4));
        *(ushort8v*)(encL + dest) = o;
      }
      __syncthreads(); /* encL + staged B chunk p visible (vmcnt drained) */

#pragma unroll
      for (int c8 = 0; c8 < 8; ++c8) {
#pragma unroll
        for (int kh = 0; kh < 2; ++kh) {
          // issue stage of chunk p+1 into the other buffer
          const int p1 = p + 1;
          if (p1 < 128) {
            const char* src = w1c + (size_t)p1 * 16384;
            const int nbuf = (kh ^ 1) * 16384;
            gload_lds16(src + sbase0 + glane, Bl + nbuf + sbase0);
            gload_lds16(src + sbase1 + glane, Bl + nbuf + sbase1);
          }
          // compute phase p from buffer kh
          const int cbuf = kh * 16384;
#pragma unroll
          for (int kk = 0; kk < 4; ++kk) {
            const int koff = (((kh * 4 + kk) * 64) + lg * 16) ^ aswz;
            const bf16x8 a0 = *(const bf16x8*)(encL + abase0 + koff);
            const bf16x8 a1 = *(const bf16x8*)(encL + abase0 + 8192 + koff);
            const bf16x8 b0 = *(const bf16x8*)(Bl + cbuf + bbase +
                                               ((kk * 64 + lg * 16) ^ bswz));
            acc[c8][0] = __builtin_amdgcn_mfma_f32_16x16x32_bf16(a0, b0, acc[c8][0], 0, 0, 0);
            acc[c8][1] = __builtin_amdgcn_mfma_f32_16x16x32_bf16(a1, b0, acc[c8][1], 0, 0, 0);
          }
          __syncthreads(); /* drains stage(p+1); all reads of buf kh done */
          ++p;
        }
      }
    }

    // half-epilogue: tanh + v-weighted column reduction, frees acc
#pragma unroll
    for (int c8 = 0; c8 < 8; ++c8) {
      const int colA = hh * 512 + c8 * 64 + wc * 16 + lm;
      const float uu = ub[colA], vv = vvec[colA];
#pragma unroll
      for (int j = 0; j < 4; ++j) {
        rowp0[j] += ftanh(acc[c8][0][j] + uu) * vv;
        rowp1[j] += ftanh(acc[c8][1][j] + uu) * vv;
      }
    }
  }

  // reduce over the 16 col-lanes (lm) of each fragment group
#pragma unroll
  for (int m = 1; m < 16; m <<= 1) {
#pragma unroll
    for (int j = 0; j < 4; ++j) {
      rowp0[j] += __shfl_xor(rowp0[j], m, 64);
      rowp1[j] += __shfl_xor(rowp1[j], m, 64);
    }
  }
  if (lm == 0) {
#pragma unroll
    for (int j = 0; j < 4; ++j) {
      sred[wc * 64 + wr * 32 + lg * 4 + j] = rowp0[j];
      sred[wc * 64 + wr * 32 + 16 + lg * 4 + j] = rowp1[j];
    }
  }
  __syncthreads();
  if (t < 64) {
    out[32768 + m0 + t] =
        sred[t] + sred[64 + t] + sred[128 + t] + sred[192 + t];
  }
}

// ---------------- masked softmax over L, in place on out[32768..] --------
__global__ __launch_bounds__(256) void softmax_kernel(
    float* __restrict__ out, const int* __restrict__ mask) {
  __shared__ float wred[4];
  const int bidx = blockIdx.x;
  const int t = threadIdx.x;
  float* sc = out + 32768 + (size_t)bidx * 2048;
  const int* mk = mask + (size_t)bidx * 2048;
  const float4 s0 = *(const float4*)(sc + t * 8);
  const float4 s1 = *(const float4*)(sc + t * 8 + 4);
  const int4 q0 = *(const int4*)(mk + t * 8);
  const int4 q1 = *(const int4*)(mk + t * 8 + 4);
  float v[8] = {s0.x, s0.y, s0.z, s0.w, s1.x, s1.y, s1.z, s1.w};
  int q[8] = {q0.x, q0.y, q0.z, q0.w, q1.x, q1.y, q1.z, q1.w};
  float mx = -3.0e38f;
#pragma unroll
  for (int j = 0; j < 8; ++j) if (q[j] != 0) mx = fmaxf(mx, v[j]);
#pragma unroll
  for (int m = 1; m < 64; m <<= 1) mx = fmaxf(mx, __shfl_xor(mx, m, 64));
  if ((t & 63) == 0) wred[t >> 6] = mx;
  __syncthreads();
  mx = fmaxf(fmaxf(wred[0], wred[1]), fmaxf(wred[2], wred[3]));
  __syncthreads();
  float pp[8]; float sum = 0.f;
#pragma unroll
  for (int j = 0; j < 8; ++j) {
    pp[j] = (q[j] != 0) ? __expf(v[j] - mx) : 0.f;
    sum += pp[j];
  }
#pragma unroll
  for (int m = 1; m < 64; m <<= 1) sum += __shfl_xor(sum, m, 64);
  if ((t & 63) == 0) wred[t >> 6] = sum;
  __syncthreads();
  sum = (wred[0] + wred[1]) + (wred[2] + wred[3]);
  const float inv = 1.0f / sum;
  const float4 o0 = {pp[0] * inv, pp[1] * inv, pp[2] * inv, pp[3] * inv};
  const float4 o1 = {pp[4] * inv, pp[5] * inv, pp[6] * inv, pp[7] * inv};
  *(float4*)(sc + t * 8) = o0;
  *(float4*)(sc + t * 8 + 4) = o1;
}

// ---------------- context[b][e] = sum_l attn[b][l] * enc[b][l][e] --------
__global__ __launch_bounds__(256) void context_kernel(
    const float* __restrict__ enc, float* __restrict__ out) {
  __shared__ __align__(16) float attnS[2048];
  __shared__ __align__(16) float red[8 * 128];
  const int bid = blockIdx.x;
  const int b = bid >> 3, ec = bid & 7;
  const int e0 = ec * 128;
  const int t = threadIdx.x;
  const float* attn = out + 32768 + (size_t)b * 2048;
#pragma unroll
  for (int i = 0; i < 8; ++i) attnS[i * 256 + t] = attn[i * 256 + t];
  __syncthreads();
  const int el = (t & 31) * 4;
  const int ls = t >> 5;
  f32x4 acc = {0.f, 0.f, 0.f, 0.f};
  const float* ebase = enc + (size_t)b * 2048 * 1024 + e0 + el;
  for (int l2 = ls; l2 < 2048; l2 += 8) {
    const float a = attnS[l2];
    const float4 ev = *(const float4*)(ebase + (size_t)l2 * 1024);
    acc[0] = fmaf(a, ev.x, acc[0]);
    acc[1] = fmaf(a, ev.y, acc[1]);
    acc[2] = fmaf(a, ev.z, acc[2]);
    acc[3] = fmaf(a, ev.w, acc[3]);
  }
  *(f32x4*)(red + ls * 128 + el) = acc;
  __syncthreads();
  if (t < 128) {
    float s = 0.f;
#pragma unroll
    for (int i = 0; i < 8; ++i) s += red[i * 128 + t];
    out[(size_t)b * 1024 + e0 + t] = s;
  }
}

extern "C" void kernel_launch(void* const* d_in, const int* in_sizes, int n_in,
                              void* d_out, int out_size, void* d_ws,
                              size_t ws_size, hipStream_t stream) {
  const float* enc = (const float*)d_in[0];
  const float* dec = (const float*)d_in[1];
  const int* mask = (const int*)d_in[2];
  const float* W1 = (const float*)d_in[3];
  const float* W2 = (const float*)d_in[4];
  const float* v = (const float*)d_in[5];
  float* out = (float*)d_out;
  char* ws = (char*)d_ws;
  unsigned short* w1b = (unsigned short*)ws; /* 2 MB pre-swizzled bf16 W1 */
  float* u = (float*)(ws + (2u << 20));      /* 128 KB dec projection */

  w1cvt_kernel<<<512, 256, 0, stream>>>(W1, w1b);
  dec_proj_kernel<<<1024, 256, 0, stream>>>(dec, W2, u);
  scores_kernel<<<1024, 512, 0, stream>>>(enc, w1b, u, v, out);
  softmax_kernel<<<32, 256, 0, stream>>>(out, mask);
  context_kernel<<<256, 256, 0, stream>>>(enc, out);
}